// Round 7
// baseline (1295.072 us; speedup 1.0000x reference)
//
#include <hip/hip_runtime.h>
#include <hip/hip_bf16.h>
#include <stdint.h>

// Problem constants
#define H_DIM 4096
#define I_DIM 11008
#define M_TOK 4096   // B*S = 2*2048

typedef __attribute__((ext_vector_type(8))) short short8;    // 8 bf16 (4 VGPRs)
typedef __attribute__((ext_vector_type(4))) float f32x4;     // 4 fp32
typedef __attribute__((ext_vector_type(16))) float f32x16;   // 16 fp32 (32x32 acc)

static __device__ __forceinline__ float bf2f(unsigned short u) {
    union { uint32_t i; float f; } v; v.i = ((uint32_t)u) << 16; return v.f;
}
static __device__ __forceinline__ unsigned short f2bf(float f) {
    union { float f; uint32_t i; } v; v.f = f;
    uint32_t r = v.i + 0x7FFF + ((v.i >> 16) & 1);   // RNE
    return (unsigned short)(r >> 16);
}

// async global->LDS, 16B per lane; LDS dest is the wave-uniform base.
static __device__ __forceinline__ void gload16(const void* g, void* l) {
    __builtin_amdgcn_global_load_lds(
        (const __attribute__((address_space(1))) void*)g,
        (__attribute__((address_space(3))) void*)l, 16, 0, 0);
}

// ---------------- small conversion kernels ----------------

__global__ void k_conv_f32_bf16(const float* __restrict__ in,
                                unsigned short* __restrict__ out, int n4) {
    int stride = gridDim.x * blockDim.x;
    for (int i = blockIdx.x * blockDim.x + threadIdx.x; i < n4; i += stride) {
        f32x4 v = ((const f32x4*)in)[i];
        uint64_t p = (uint64_t)f2bf(v[0]) | ((uint64_t)f2bf(v[1]) << 16) |
                     ((uint64_t)f2bf(v[2]) << 32) | ((uint64_t)f2bf(v[3]) << 48);
        ((uint64_t*)out)[i] = p;
    }
}

// B [32][N] f32 -> BT [N][32] bf16
__global__ void k_transposeB(const float* __restrict__ in,
                             unsigned short* __restrict__ out, int N) {
    int idx = blockIdx.x * blockDim.x + threadIdx.x;
    if (idx < N * 32) {
        int n = idx >> 5, r = idx & 31;
        out[idx] = f2bf(in[r * N + n]);
    }
}

// ---------------- W_eff prep: dequant + rank-32 LR via one MFMA step ----------------
__global__ __launch_bounds__(256) void k_wprep(
    const unsigned short* __restrict__ BT,   // [Nw][32] bf16
    const unsigned short* __restrict__ Abf,  // [Kw][32] bf16
    const int* __restrict__ q,               // [Nw][Kw] int32
    const float* __restrict__ scale,         // [Nw]
    unsigned short* __restrict__ W,          // [Nw][Kw] bf16 out
    int Nw, int Kw)
{
    __shared__ unsigned short As[128 * 32];
    __shared__ unsigned short Bs[128 * 32];
    const int tid = threadIdx.x, wid = tid >> 6, lane = tid & 63;
    const int wr = wid >> 1, wc = wid & 1;
    const int brow = blockIdx.y * 128;   // n
    const int bcol = blockIdx.x * 128;   // k
    const int srow = wid * 16 + (lane >> 2), scol = (lane & 3) * 8;

    gload16(BT + (size_t)(brow + srow) * 32 + scol,        &As[wid * 512]);
    gload16(BT + (size_t)(brow + 64 + srow) * 32 + scol,   &As[wid * 512 + 2048]);
    gload16(Abf + (size_t)(bcol + srow) * 32 + scol,       &Bs[wid * 512]);
    gload16(Abf + (size_t)(bcol + 64 + srow) * 32 + scol,  &Bs[wid * 512 + 2048]);
    __syncthreads();

    const int fr = lane & 15, kg = (lane >> 4) * 8;
    f32x4 acc[4][4] = {};
    short8 af[4], bfr[4];
#pragma unroll
    for (int i = 0; i < 4; i++)
        af[i] = *(const short8*)&As[(wr * 64 + i * 16 + fr) * 32 + kg];
#pragma unroll
    for (int j = 0; j < 4; j++)
        bfr[j] = *(const short8*)&Bs[(wc * 64 + j * 16 + fr) * 32 + kg];
#pragma unroll
    for (int i = 0; i < 4; i++)
#pragma unroll
        for (int j = 0; j < 4; j++)
            acc[i][j] = __builtin_amdgcn_mfma_f32_16x16x32_bf16(af[i], bfr[j], acc[i][j], 0, 0, 0);

    const int q4 = lane >> 4;
#pragma unroll
    for (int i = 0; i < 4; i++) {
#pragma unroll
        for (int t = 0; t < 4; t++) {
            int n = brow + wr * 64 + i * 16 + q4 * 4 + t;
            float sc = scale[n] * 0.005f;
#pragma unroll
            for (int j = 0; j < 4; j++) {
                int k = bcol + wc * 64 + j * 16 + fr;
                size_t off = (size_t)n * Kw + k;
                float w = ((float)q[off] - 7.5f) * sc + 0.02f * acc[i][j][t];
                W[off] = f2bf(w);
            }
        }
    }
}

// ---------------- main bf16 GEMM: 256x256, BK=64, 32x32x16 MFMA, 4-phase ----------
// C[M][N] = A[M][K] @ B[N][K]^T ; EPI: 0 bf16, 1 h=silu(g)*acc bf16, 2 f32
// 512 threads = 8 waves (2M x 4N); per-wave C 128x64 = 4x2 frags of 32x32.
// Per K-tile: 4 phases = k-slices ks=0..3, each {6 ds_read_b128 for ks+1 ;
// barrier ; 8 independent MFMA(ks)}. Every A/B fragment read exactly once
// (24 b128/wave/tile). All 8 stage-gloads of tile t+2 batched at P3
// post-barrier (target region's last read is 2 barriers + ~900cy HBM earlier).
// PUBLISH RULE (R6 race fix): the next-tile ks0 reads are issued AFTER the P3
// barrier. Certificate = per-wave vmcnt(0) BEFORE the barrier + the barrier
// itself (vmcnt is per-wave; fragment rows span all 8 waves' staging loads,
// so cross-wave reads are only safe after every wave passed its own vmcnt).
// A-frag(mg,ks): lane l -> row wr*128+mg*32+(l&31), k = ks*16+(l>>5)*8+[0..8)
// B-frag(ng,ks): lane l -> col wc*64+ng*32+(l&31), same k mapping.
// C/D (verified m74/m101): col=lane&31, row=(r&3)+8*(r>>2)+4*(lane>>5).
template <int EPI>
__global__ __launch_bounds__(512, 1) void k_gemm256(
    const unsigned short* __restrict__ A,   // [M][K] bf16
    const unsigned short* __restrict__ B,   // [N][K] bf16
    void* __restrict__ C,
    const unsigned short* __restrict__ Gin, // EPI==1: g buffer
    int M, int N, int K)
{
    extern __shared__ unsigned short smem[];   // 65536 elems = 128 KiB
    const int tid = threadIdx.x, wid = tid >> 6, lane = tid & 63;
    const int wr = wid >> 2, wc = wid & 3;

    // T1: bijective XCD swizzle
    const int gx = N >> 8;
    const int nwg = gx * (M >> 8);
    int orig = blockIdx.y * gx + blockIdx.x;
    int q8 = nwg >> 3, r8 = nwg & 7;
    int xcd = orig & 7, lid = orig >> 3;
    int wg = (xcd < r8 ? xcd * (q8 + 1) : r8 * (q8 + 1) + (xcd - r8) * q8) + lid;
    const int bcol = (wg % gx) << 8;
    const int brow = (wg / gx) << 8;

    // staging: quarter c covers rows [c*64 + wid*8, +8); lane l -> row l>>3,
    // LDS slot l&7, pre-swizzled global source slot (l&7)^(l>>3)
    const int rg = lane >> 3;
    const int ss = ((lane & 7) ^ rg) * 8;
    const unsigned short* aS[4];
    const unsigned short* bS[4];
#pragma unroll
    for (int c = 0; c < 4; c++) {
        int row = c * 64 + wid * 8 + rg;
        aS[c] = A + (size_t)(brow + row) * K + ss;
        bS[c] = B + (size_t)(bcol + row) * K + ss;
    }
    const int ldw = wid * 512;   // wave chunk within a 64-row quarter (elems)

    f32x16 acc[4][2];
#pragma unroll
    for (int mg = 0; mg < 4; ++mg)
#pragma unroll
        for (int ng = 0; ng < 2; ++ng)
#pragma unroll
            for (int r = 0; r < 16; ++r) acc[mg][ng][r] = 0.0f;

    short8 afX[4], afY[4], bfX[2], bfY[2];
    const int l31 = lane & 31, kg = lane >> 5, r7 = l31 & 7;
    const int NT = K >> 6;

    // per-buffer per-lane LDS read bases (XOR swizzle mask r7 is mg/ng-invariant)
    const unsigned short* aB[2];
    const unsigned short* bB[2];
    aB[0] = smem + (wr * 128 + l31) * 64;
    aB[1] = aB[0] + 32768;
    bB[0] = smem + 16384 + (wc * 64 + l31) * 64;
    bB[1] = bB[0] + 32768;

#define STG(p, k0, doff) gload16((p) + (k0), smem + (doff) + ldw)
#define STAGE8(BB, k0) { \
    STG(aS[0], k0, (BB)*32768);           STG(aS[1], k0, (BB)*32768 + 4096); \
    STG(aS[2], k0, (BB)*32768 + 8192);    STG(aS[3], k0, (BB)*32768 + 12288); \
    STG(bS[0], k0, (BB)*32768 + 16384);   STG(bS[1], k0, (BB)*32768 + 20480); \
    STG(bS[2], k0, (BB)*32768 + 24576);   STG(bS[3], k0, (BB)*32768 + 28672); }
#define LDA(dst, BB, ks) { const int c_ = ((((ks) << 1) | kg) ^ r7) << 3; \
    _Pragma("unroll") for (int mg = 0; mg < 4; ++mg) \
        dst[mg] = *(const short8*)&aB[BB][mg * 2048 + c_]; }
#define LDB(dst, BB, ks) { const int c_ = ((((ks) << 1) | kg) ^ r7) << 3; \
    _Pragma("unroll") for (int ng = 0; ng < 2; ++ng) \
        dst[ng] = *(const short8*)&bB[BB][ng * 2048 + c_]; }
#define MFQ(AF, BF) { __builtin_amdgcn_s_setprio(1); \
    _Pragma("unroll") for (int mg = 0; mg < 4; ++mg) \
    _Pragma("unroll") for (int ng = 0; ng < 2; ++ng) \
        acc[mg][ng] = __builtin_amdgcn_mfma_f32_32x32x16_bf16( \
            AF[mg], BF[ng], acc[mg][ng], 0, 0, 0); \
    __builtin_amdgcn_s_setprio(0); }

// One K-tile (4 phases). X/Y frag rotation: P0 consumes X(ks0) reads Y(ks1);
// P1 consumes Y reads X(ks2); P2 consumes X reads Y(ks3); P3 consumes Y.
// P3 publish: vmcnt(0) pre-barrier (own loads) + barrier (all waves) ->
// buf[1-BB]=tile t+1 certified block-wide; THEN read its ks0 into X (RNEXT)
// and stage tile t+2 into buf BB (S2).
#define TILE(BB, t, RNEXT, S2) { \
    LDA(afY, BB, 1); LDB(bfY, BB, 1); \
    __builtin_amdgcn_s_barrier(); \
    MFQ(afX, bfX); \
    LDA(afX, BB, 2); LDB(bfX, BB, 2); \
    __builtin_amdgcn_s_barrier(); \
    MFQ(afY, bfY); \
    LDA(afY, BB, 3); LDB(bfY, BB, 3); \
    __builtin_amdgcn_s_barrier(); \
    MFQ(afX, bfX); \
    if (RNEXT) asm volatile("s_waitcnt vmcnt(0)" ::: "memory"); \
    __builtin_amdgcn_s_barrier(); \
    if (RNEXT) { LDA(afX, 1-(BB), 0); LDB(bfX, 1-(BB), 0); } \
    if (S2) STAGE8(BB, ((t) + 2) << 6); \
    MFQ(afY, bfY); }

    // prologue: stage tiles 0 and 1 (8+8 gloads); wait tile 0 (own loads) +
    // barrier (all waves); then read tile-0 ks0 (post-barrier => safe).
    STAGE8(0, 0);
    STAGE8(1, 64);
    asm volatile("s_waitcnt vmcnt(8)" ::: "memory");
    __builtin_amdgcn_s_barrier();
    LDA(afX, 0, 0); LDB(bfX, 0, 0);

    for (int t = 0; t < NT - 2; t += 2) {
        TILE(0, t,     1, 1);
        TILE(1, t + 1, 1, 1);
    }
    TILE(0, NT - 2, 1, 0);
    TILE(1, NT - 1, 0, 0);

#undef TILE
#undef MFQ
#undef LDB
#undef LDA
#undef STAGE8
#undef STG

    // epilogue (32x32 C/D layout)
    const int q2 = lane >> 5;
#pragma unroll
    for (int mg = 0; mg < 4; ++mg) {
#pragma unroll
        for (int ng = 0; ng < 2; ++ng) {
#pragma unroll
            for (int r = 0; r < 16; ++r) {
                int m = brow + wr * 128 + mg * 32 + (r & 3) + 8 * (r >> 2) + 4 * q2;
                int n = bcol + wc * 64 + ng * 32 + l31;
                size_t off = (size_t)m * N + n;
                float v = acc[mg][ng][r];
                if (EPI == 0) {
                    ((unsigned short*)C)[off] = f2bf(v);
                } else if (EPI == 1) {
                    float g = bf2f(Gin[off]);
                    float s = g / (1.0f + __expf(-g));   // silu(g)
                    ((unsigned short*)C)[off] = f2bf(s * v);
                } else {
                    ((float*)C)[off] = v;
                }
            }
        }
    }
}

// ---------------- host launch ----------------
extern "C" void kernel_launch(void* const* d_in, const int* in_sizes, int n_in,
                              void* d_out, int out_size, void* d_ws, size_t ws_size,
                              hipStream_t stream) {
    (void)in_sizes; (void)n_in; (void)out_size; (void)ws_size;
    const float* x          = (const float*)d_in[0];
    const int*   gate_q     = (const int*)d_in[1];
    const float* gate_scale = (const float*)d_in[2];
    const float* gate_A     = (const float*)d_in[3];
    const float* gate_B     = (const float*)d_in[4];
    const int*   up_q       = (const int*)d_in[5];
    const float* up_scale   = (const float*)d_in[6];
    const float* up_A       = (const float*)d_in[7];
    const float* up_B       = (const float*)d_in[8];
    const int*   down_q     = (const int*)d_in[9];
    const float* down_scale = (const float*)d_in[10];
    const float* down_A     = (const float*)d_in[11];
    const float* down_B     = (const float*)d_in[12];

    char* ws = (char*)d_ws;
    size_t off = 0;
    auto alloc = [&](size_t bytes) {
        void* p = ws + off; off += (bytes + 255) & ~(size_t)255; return p;
    };
    unsigned short* xbf  = (unsigned short*)alloc((size_t)M_TOK * H_DIM * 2);
    unsigned short* wg   = (unsigned short*)alloc((size_t)I_DIM * H_DIM * 2);
    unsigned short* wu   = (unsigned short*)alloc((size_t)I_DIM * H_DIM * 2);
    unsigned short* wd   = (unsigned short*)alloc((size_t)H_DIM * I_DIM * 2);
    unsigned short* gbuf = (unsigned short*)alloc((size_t)M_TOK * I_DIM * 2);
    unsigned short* AgBf = (unsigned short*)alloc((size_t)H_DIM * 32 * 2);
    unsigned short* AuBf = (unsigned short*)alloc((size_t)H_DIM * 32 * 2);
    unsigned short* AdBf = (unsigned short*)alloc((size_t)I_DIM * 32 * 2);
    unsigned short* BgT  = (unsigned short*)alloc((size_t)I_DIM * 32 * 2);
    unsigned short* BuT  = (unsigned short*)alloc((size_t)I_DIM * 32 * 2);
    unsigned short* BdT  = (unsigned short*)alloc((size_t)H_DIM * 32 * 2);

    (void)hipFuncSetAttribute((const void*)k_gemm256<0>,
        hipFuncAttributeMaxDynamicSharedMemorySize, 131072);
    (void)hipFuncSetAttribute((const void*)k_gemm256<1>,
        hipFuncAttributeMaxDynamicSharedMemorySize, 131072);
    (void)hipFuncSetAttribute((const void*)k_gemm256<2>,
        hipFuncAttributeMaxDynamicSharedMemorySize, 131072);

    // small conversions
    k_conv_f32_bf16<<<128, 256, 0, stream>>>(gate_A, AgBf, (H_DIM * 32) / 4);
    k_conv_f32_bf16<<<128, 256, 0, stream>>>(up_A,   AuBf, (H_DIM * 32) / 4);
    k_conv_f32_bf16<<<344, 256, 0, stream>>>(down_A, AdBf, (I_DIM * 32) / 4);
    k_transposeB<<<(I_DIM * 32 + 255) / 256, 256, 0, stream>>>(gate_B, BgT, I_DIM);
    k_transposeB<<<(I_DIM * 32 + 255) / 256, 256, 0, stream>>>(up_B,   BuT, I_DIM);
    k_transposeB<<<(H_DIM * 32 + 255) / 256, 256, 0, stream>>>(down_B, BdT, H_DIM);
    k_conv_f32_bf16<<<2048, 256, 0, stream>>>(x, xbf, (M_TOK * H_DIM) / 4);

    // W_eff = dequant + 0.02*(A@B)^T   (bf16)
    k_wprep<<<dim3(H_DIM / 128, I_DIM / 128), 256, 0, stream>>>(BgT, AgBf, gate_q, gate_scale, wg, I_DIM, H_DIM);
    k_wprep<<<dim3(H_DIM / 128, I_DIM / 128), 256, 0, stream>>>(BuT, AuBf, up_q,   up_scale,   wu, I_DIM, H_DIM);
    k_wprep<<<dim3(I_DIM / 128, H_DIM / 128), 256, 0, stream>>>(BdT, AdBf, down_q, down_scale, wd, H_DIM, I_DIM);

    // g = x @ Wg^T          (bf16 out)
    k_gemm256<0><<<dim3(I_DIM / 256, M_TOK / 256), 512, 131072, stream>>>(xbf, wg, gbuf, nullptr, M_TOK, I_DIM, H_DIM);
    // h = silu(g) * (x @ Wu^T)   (in-place over g)
    k_gemm256<1><<<dim3(I_DIM / 256, M_TOK / 256), 512, 131072, stream>>>(xbf, wu, gbuf, gbuf, M_TOK, I_DIM, H_DIM);
    // out = h @ Wd^T        (f32)
    k_gemm256<2><<<dim3(H_DIM / 256, M_TOK / 256), 512, 131072, stream>>>(gbuf, wd, d_out, nullptr, M_TOK, H_DIM, I_DIM);
}

// Round 8
// 1223.118 us; speedup vs baseline: 1.0588x; 1.0588x over previous
//
#include <hip/hip_runtime.h>
#include <hip/hip_bf16.h>
#include <stdint.h>

// Problem constants
#define H_DIM 4096
#define I_DIM 11008
#define M_TOK 4096   // B*S = 2*2048

typedef __attribute__((ext_vector_type(8))) short short8;  // 8 bf16 (4 VGPRs)
typedef __attribute__((ext_vector_type(4))) float f32x4;   // 4 fp32

static __device__ __forceinline__ float bf2f(unsigned short u) {
    union { uint32_t i; float f; } v; v.i = ((uint32_t)u) << 16; return v.f;
}
static __device__ __forceinline__ unsigned short f2bf(float f) {
    union { float f; uint32_t i; } v; v.f = f;
    uint32_t r = v.i + 0x7FFF + ((v.i >> 16) & 1);   // RNE
    return (unsigned short)(r >> 16);
}

// async global->LDS, 16B per lane; LDS dest is the wave-uniform base.
static __device__ __forceinline__ void gload16(const void* g, void* l) {
    __builtin_amdgcn_global_load_lds(
        (const __attribute__((address_space(1))) void*)g,
        (__attribute__((address_space(3))) void*)l, 16, 0, 0);
}

// ---------------- small conversion kernels ----------------

__global__ void k_conv_f32_bf16(const float* __restrict__ in,
                                unsigned short* __restrict__ out, int n4) {
    int stride = gridDim.x * blockDim.x;
    for (int i = blockIdx.x * blockDim.x + threadIdx.x; i < n4; i += stride) {
        f32x4 v = ((const f32x4*)in)[i];
        uint64_t p = (uint64_t)f2bf(v[0]) | ((uint64_t)f2bf(v[1]) << 16) |
                     ((uint64_t)f2bf(v[2]) << 32) | ((uint64_t)f2bf(v[3]) << 48);
        ((uint64_t*)out)[i] = p;
    }
}

// B [32][N] f32 -> BT [N][32] bf16
__global__ void k_transposeB(const float* __restrict__ in,
                             unsigned short* __restrict__ out, int N) {
    int idx = blockIdx.x * blockDim.x + threadIdx.x;
    if (idx < N * 32) {
        int n = idx >> 5, r = idx & 31;
        out[idx] = f2bf(in[r * N + n]);
    }
}

// ---------------- W_eff prep: dequant + rank-32 LR via one MFMA step ----------------
__global__ __launch_bounds__(256) void k_wprep(
    const unsigned short* __restrict__ BT,   // [Nw][32] bf16
    const unsigned short* __restrict__ Abf,  // [Kw][32] bf16
    const int* __restrict__ q,               // [Nw][Kw] int32
    const float* __restrict__ scale,         // [Nw]
    unsigned short* __restrict__ W,          // [Nw][Kw] bf16 out
    int Nw, int Kw)
{
    __shared__ unsigned short As[128 * 32];
    __shared__ unsigned short Bs[128 * 32];
    const int tid = threadIdx.x, wid = tid >> 6, lane = tid & 63;
    const int wr = wid >> 1, wc = wid & 1;
    const int brow = blockIdx.y * 128;   // n
    const int bcol = blockIdx.x * 128;   // k
    const int srow = wid * 16 + (lane >> 2), scol = (lane & 3) * 8;

    gload16(BT + (size_t)(brow + srow) * 32 + scol,        &As[wid * 512]);
    gload16(BT + (size_t)(brow + 64 + srow) * 32 + scol,   &As[wid * 512 + 2048]);
    gload16(Abf + (size_t)(bcol + srow) * 32 + scol,       &Bs[wid * 512]);
    gload16(Abf + (size_t)(bcol + 64 + srow) * 32 + scol,  &Bs[wid * 512 + 2048]);
    __syncthreads();

    const int fr = lane & 15, kg = (lane >> 4) * 8;
    f32x4 acc[4][4] = {};
    short8 af[4], bfr[4];
#pragma unroll
    for (int i = 0; i < 4; i++)
        af[i] = *(const short8*)&As[(wr * 64 + i * 16 + fr) * 32 + kg];
#pragma unroll
    for (int j = 0; j < 4; j++)
        bfr[j] = *(const short8*)&Bs[(wc * 64 + j * 16 + fr) * 32 + kg];
#pragma unroll
    for (int i = 0; i < 4; i++)
#pragma unroll
        for (int j = 0; j < 4; j++)
            acc[i][j] = __builtin_amdgcn_mfma_f32_16x16x32_bf16(af[i], bfr[j], acc[i][j], 0, 0, 0);

    const int q4 = lane >> 4;
#pragma unroll
    for (int i = 0; i < 4; i++) {
#pragma unroll
        for (int t = 0; t < 4; t++) {
            int n = brow + wr * 64 + i * 16 + q4 * 4 + t;
            float sc = scale[n] * 0.005f;
#pragma unroll
            for (int j = 0; j < 4; j++) {
                int k = bcol + wc * 64 + j * 16 + fr;
                size_t off = (size_t)n * Kw + k;
                float w = ((float)q[off] - 7.5f) * sc + 0.02f * acc[i][j][t];
                W[off] = f2bf(w);
            }
        }
    }
}

// ---------------- main bf16 GEMM: m201 8-phase template, 256x256, BK=64 -----------
// C[M][N] = A[M][K] @ B[N][K]^T ; EPI: 0 bf16, 1 h=silu(g)*acc bf16, 2 f32
// 512 threads = 8 waves (2M x 4N); per-wave C 128x64 (8i x 4j 16x16 frags).
// Iter = 2 K-tiles: tile a=2u (dbuf0, ph0-3), tile b=2u+1 (dbuf1, ph4-7).
// Phase = one C-quadrant (ih,jh) x K=64: 16 MFMA. Order (0,0),(0,1),(1,1),(1,0).
// Per phase: [ds_reads for THIS phase] [stage 1 half-tile (2 gloads)]
//            [vmcnt cert at ph3/ph7, pre-barrier] barrier ; setprio 16 MFMA ; barrier.
// Stage calendar (iter u): ph0:B0(b,dbuf1) ph1:A0(a',dbuf0) ph2:B1(a') ph3:A1(a')
//   ph4:B0(a') ph5:A0(b',dbuf1) ph6:B1(b') ph7:A1(b')   [a'=2u+2, b'=2u+3]
// Certs: ph3 vmcnt(6) drains prev ph5,6,7 + this ph0 = tile b complete (read ph4);
//        ph7 vmcnt(6) drains ph1..ph4 = tile a' complete (read next ph0).
// Every stage overwrites a region whose last reader finished >=1 trailing barrier
// earlier. B0 held in bf0 regs across ph0-ph3 (no re-read).
// Read geometry = R5's proven conflict-free pattern (16 rows x 4 XOR slots).
template <int EPI>
__global__ __launch_bounds__(512, 1) void k_gemm256(
    const unsigned short* __restrict__ A,   // [M][K] bf16
    const unsigned short* __restrict__ B,   // [N][K] bf16
    void* __restrict__ C,
    const unsigned short* __restrict__ Gin, // EPI==1: g buffer
    int M, int N, int K)
{
    extern __shared__ unsigned short smem[];   // 65536 elems = 128 KiB
    const int tid = threadIdx.x, wid = tid >> 6, lane = tid & 63;
    const int wr = wid >> 2, wc = wid & 3;

    // T1: bijective XCD swizzle
    const int gx = N >> 8;
    const int nwg = gx * (M >> 8);
    int orig = blockIdx.y * gx + blockIdx.x;
    int q8 = nwg >> 3, r8 = nwg & 7;
    int xcd = orig & 7, lid = orig >> 3;
    int wg = (xcd < r8 ? xcd * (q8 + 1) : r8 * (q8 + 1) + (xcd - r8) * q8) + lid;
    const int bcol = (wg % gx) << 8;
    const int brow = (wg / gx) << 8;

    // staging: quarter c = h*2+g covers rows [c*64 + wid*8, +8); lane l ->
    // row c*64+wid*8+(l>>3), LDS slot l&7, pre-swizzled source slot (l&7)^(l>>3)
    const int rg = lane >> 3;
    const int ss = ((lane & 7) ^ rg) * 8;
    const unsigned short* aS[4];
    const unsigned short* bS[4];
#pragma unroll
    for (int c = 0; c < 4; c++) {
        int row = c * 64 + wid * 8 + rg;
        aS[c] = A + (size_t)(brow + row) * K + ss;
        bS[c] = B + (size_t)(bcol + row) * K + ss;
    }
    const int ldw = wid * 512;

    f32x4 acc[8][4] = {};
    short8 af[4][2];    // A-half frags for current quadrant pair
    short8 bf0[2][2];   // B-half0 (persists ph0..ph3 of each half-iter)
    short8 bf1[2][2];   // B-half1
    const int fr = lane & 15, qk = lane >> 4, f7 = fr & 7;
    const int NT = K >> 6, NU = NT >> 1;
    const int co0 = (qk ^ f7) << 3, co1 = ((4 | qk) ^ f7) << 3;
    const unsigned short* aR = smem + (wr * 64 + fr) * 64;
    const unsigned short* bR = smem + 16384 + (wc * 32 + fr) * 64;

#define SHA(D, H, K0) { \
    gload16(aS[(H)*2+0] + (K0), smem + (D)*32768 + (H)*8192 + ldw); \
    gload16(aS[(H)*2+1] + (K0), smem + (D)*32768 + (H)*8192 + 4096 + ldw); }
#define SHB(D, H, K0) { \
    gload16(bS[(H)*2+0] + (K0), smem + (D)*32768 + 16384 + (H)*8192 + ldw); \
    gload16(bS[(H)*2+1] + (K0), smem + (D)*32768 + 16384 + (H)*8192 + 4096 + ldw); }
#define LDA(D, IH) { _Pragma("unroll") for (int i4 = 0; i4 < 4; ++i4) { \
    af[i4][0] = *(const short8*)&aR[(D)*32768 + (IH)*8192 + i4*1024 + co0]; \
    af[i4][1] = *(const short8*)&aR[(D)*32768 + (IH)*8192 + i4*1024 + co1]; } }
#define LDB(DST, D, JH) { _Pragma("unroll") for (int j2 = 0; j2 < 2; ++j2) { \
    DST[j2][0] = *(const short8*)&bR[(D)*32768 + (JH)*8192 + j2*1024 + co0]; \
    DST[j2][1] = *(const short8*)&bR[(D)*32768 + (JH)*8192 + j2*1024 + co1]; } }
#define MFQ(IH, JH, BF) { __builtin_amdgcn_s_setprio(1); \
    _Pragma("unroll") for (int i4 = 0; i4 < 4; ++i4) \
    _Pragma("unroll") for (int j2 = 0; j2 < 2; ++j2) { \
        acc[(IH)*4+i4][(JH)*2+j2] = __builtin_amdgcn_mfma_f32_16x16x32_bf16( \
            af[i4][0], BF[j2][0], acc[(IH)*4+i4][(JH)*2+j2], 0, 0, 0); \
        acc[(IH)*4+i4][(JH)*2+j2] = __builtin_amdgcn_mfma_f32_16x16x32_bf16( \
            af[i4][1], BF[j2][1], acc[(IH)*4+i4][(JH)*2+j2], 0, 0, 0); } \
    __builtin_amdgcn_s_setprio(0); }
#define BAR() __builtin_amdgcn_s_barrier()

    auto ITER = [&](int ka, int kb, bool full) {
        const int ka2 = ka + 128, kb2 = kb + 128;
        // ---- dbuf0 tile (ph0-3) ----
        LDA(0, 0); LDB(bf0, 0, 0);
        SHB(1, 0, kb);                       // B0 of dbuf1 tile (read at ph4)
        BAR(); MFQ(0, 0, bf0); BAR();
        LDB(bf1, 0, 1);
        if (full) SHA(0, 0, ka2);
        BAR(); MFQ(0, 1, bf1); BAR();
        LDA(0, 1);
        if (full) SHB(0, 1, ka2);
        BAR(); MFQ(1, 1, bf1); BAR();
        if (full) { SHA(0, 1, ka2);
                    asm volatile("s_waitcnt vmcnt(6)" ::: "memory"); }
        else      { asm volatile("s_waitcnt vmcnt(0)" ::: "memory"); }
        BAR(); MFQ(1, 0, bf0); BAR();
        // ---- dbuf1 tile (ph4-7) ----
        LDA(1, 0); LDB(bf0, 1, 0);
        if (full) SHB(0, 0, ka2);
        BAR(); MFQ(0, 0, bf0); BAR();
        LDB(bf1, 1, 1);
        if (full) SHA(1, 0, kb2);
        BAR(); MFQ(0, 1, bf1); BAR();
        LDA(1, 1);
        if (full) SHB(1, 1, kb2);
        BAR(); MFQ(1, 1, bf1); BAR();
        if (full) { SHA(1, 1, kb2);
                    asm volatile("s_waitcnt vmcnt(6)" ::: "memory"); }
        BAR(); MFQ(1, 0, bf0); BAR();
    };

    // prologue: tile0 full (8 loads) + tile1 A0,B1,A1 (6 loads; B0 at ph0).
    SHA(0, 0, 0); SHB(0, 0, 0); SHB(0, 1, 0); SHA(0, 1, 0);
    SHA(1, 0, 64); SHB(1, 1, 64); SHA(1, 1, 64);
    asm volatile("s_waitcnt vmcnt(6)" ::: "memory");   // tile 0 landed
    BAR();

    for (int u = 0; u < NU - 1; ++u) ITER(u * 128, u * 128 + 64, true);
    ITER((NU - 1) * 128, (NU - 1) * 128 + 64, false);

#undef BAR
#undef MFQ
#undef LDB
#undef LDA
#undef SHB
#undef SHA

    // epilogue
    const int q4 = lane >> 4;
#pragma unroll
    for (int i = 0; i < 8; ++i) {
#pragma unroll
        for (int j = 0; j < 4; ++j) {
#pragma unroll
            for (int tt = 0; tt < 4; ++tt) {
                int m = brow + (i >> 2) * 128 + wr * 64 + (i & 3) * 16 + q4 * 4 + tt;
                int n = bcol + (j >> 1) * 128 + wc * 32 + (j & 1) * 16 + fr;
                size_t off = (size_t)m * N + n;
                float v = acc[i][j][tt];
                if (EPI == 0) {
                    ((unsigned short*)C)[off] = f2bf(v);
                } else if (EPI == 1) {
                    float g = bf2f(Gin[off]);
                    float s = g / (1.0f + __expf(-g));   // silu(g)
                    ((unsigned short*)C)[off] = f2bf(s * v);
                } else {
                    ((float*)C)[off] = v;
                }
            }
        }
    }
}

// ---------------- host launch ----------------
extern "C" void kernel_launch(void* const* d_in, const int* in_sizes, int n_in,
                              void* d_out, int out_size, void* d_ws, size_t ws_size,
                              hipStream_t stream) {
    (void)in_sizes; (void)n_in; (void)out_size; (void)ws_size;
    const float* x          = (const float*)d_in[0];
    const int*   gate_q     = (const int*)d_in[1];
    const float* gate_scale = (const float*)d_in[2];
    const float* gate_A     = (const float*)d_in[3];
    const float* gate_B     = (const float*)d_in[4];
    const int*   up_q       = (const int*)d_in[5];
    const float* up_scale   = (const float*)d_in[6];
    const float* up_A       = (const float*)d_in[7];
    const float* up_B       = (const float*)d_in[8];
    const int*   down_q     = (const int*)d_in[9];
    const float* down_scale = (const float*)d_in[10];
    const float* down_A     = (const float*)d_in[11];
    const float* down_B     = (const float*)d_in[12];

    char* ws = (char*)d_ws;
    size_t off = 0;
    auto alloc = [&](size_t bytes) {
        void* p = ws + off; off += (bytes + 255) & ~(size_t)255; return p;
    };
    unsigned short* xbf  = (unsigned short*)alloc((size_t)M_TOK * H_DIM * 2);
    unsigned short* wg   = (unsigned short*)alloc((size_t)I_DIM * H_DIM * 2);
    unsigned short* wu   = (unsigned short*)alloc((size_t)I_DIM * H_DIM * 2);
    unsigned short* wd   = (unsigned short*)alloc((size_t)H_DIM * I_DIM * 2);
    unsigned short* gbuf = (unsigned short*)alloc((size_t)M_TOK * I_DIM * 2);
    unsigned short* AgBf = (unsigned short*)alloc((size_t)H_DIM * 32 * 2);
    unsigned short* AuBf = (unsigned short*)alloc((size_t)H_DIM * 32 * 2);
    unsigned short* AdBf = (unsigned short*)alloc((size_t)I_DIM * 32 * 2);
    unsigned short* BgT  = (unsigned short*)alloc((size_t)I_DIM * 32 * 2);
    unsigned short* BuT  = (unsigned short*)alloc((size_t)I_DIM * 32 * 2);
    unsigned short* BdT  = (unsigned short*)alloc((size_t)H_DIM * 32 * 2);

    (void)hipFuncSetAttribute((const void*)k_gemm256<0>,
        hipFuncAttributeMaxDynamicSharedMemorySize, 131072);
    (void)hipFuncSetAttribute((const void*)k_gemm256<1>,
        hipFuncAttributeMaxDynamicSharedMemorySize, 131072);
    (void)hipFuncSetAttribute((const void*)k_gemm256<2>,
        hipFuncAttributeMaxDynamicSharedMemorySize, 131072);

    // small conversions
    k_conv_f32_bf16<<<128, 256, 0, stream>>>(gate_A, AgBf, (H_DIM * 32) / 4);
    k_conv_f32_bf16<<<128, 256, 0, stream>>>(up_A,   AuBf, (H_DIM * 32) / 4);
    k_conv_f32_bf16<<<344, 256, 0, stream>>>(down_A, AdBf, (I_DIM * 32) / 4);
    k_transposeB<<<(I_DIM * 32 + 255) / 256, 256, 0, stream>>>(gate_B, BgT, I_DIM);
    k_transposeB<<<(I_DIM * 32 + 255) / 256, 256, 0, stream>>>(up_B,   BuT, I_DIM);
    k_transposeB<<<(H_DIM * 32 + 255) / 256, 256, 0, stream>>>(down_B, BdT, H_DIM);
    k_conv_f32_bf16<<<2048, 256, 0, stream>>>(x, xbf, (M_TOK * H_DIM) / 4);

    // W_eff = dequant + 0.02*(A@B)^T   (bf16)
    k_wprep<<<dim3(H_DIM / 128, I_DIM / 128), 256, 0, stream>>>(BgT, AgBf, gate_q, gate_scale, wg, I_DIM, H_DIM);
    k_wprep<<<dim3(H_DIM / 128, I_DIM / 128), 256, 0, stream>>>(BuT, AuBf, up_q,   up_scale,   wu, I_DIM, H_DIM);
    k_wprep<<<dim3(I_DIM / 128, H_DIM / 128), 256, 0, stream>>>(BdT, AdBf, down_q, down_scale, wd, H_DIM, I_DIM);

    // g = x @ Wg^T          (bf16 out)
    k_gemm256<0><<<dim3(I_DIM / 256, M_TOK / 256), 512, 131072, stream>>>(xbf, wg, gbuf, nullptr, M_TOK, I_DIM, H_DIM);
    // h = silu(g) * (x @ Wu^T)   (in-place over g)
    k_gemm256<1><<<dim3(I_DIM / 256, M_TOK / 256), 512, 131072, stream>>>(xbf, wu, gbuf, gbuf, M_TOK, I_DIM, H_DIM);
    // out = h @ Wd^T        (f32)
    k_gemm256<2><<<dim3(H_DIM / 256, M_TOK / 256), 512, 131072, stream>>>(gbuf, wd, d_out, nullptr, M_TOK, H_DIM, I_DIM);
}

// Round 9
// 1221.007 us; speedup vs baseline: 1.0607x; 1.0017x over previous
//
#include <hip/hip_runtime.h>
#include <hip/hip_bf16.h>
#include <stdint.h>

// Problem constants
#define H_DIM 4096
#define I_DIM 11008
#define M_TOK 4096   // B*S = 2*2048

typedef __attribute__((ext_vector_type(8))) short short8;  // 8 bf16 (4 VGPRs)
typedef __attribute__((ext_vector_type(4))) float f32x4;   // 4 fp32

static __device__ __forceinline__ float bf2f(unsigned short u) {
    union { uint32_t i; float f; } v; v.i = ((uint32_t)u) << 16; return v.f;
}
static __device__ __forceinline__ unsigned short f2bf(float f) {
    union { float f; uint32_t i; } v; v.f = f;
    uint32_t r = v.i + 0x7FFF + ((v.i >> 16) & 1);   // RNE
    return (unsigned short)(r >> 16);
}

// async global->LDS, 16B per lane; LDS dest is the wave-uniform base.
static __device__ __forceinline__ void gload16(const void* g, void* l) {
    __builtin_amdgcn_global_load_lds(
        (const __attribute__((address_space(1))) void*)g,
        (__attribute__((address_space(3))) void*)l, 16, 0, 0);
}

// ---------------- small conversion kernels ----------------

__global__ void k_conv_f32_bf16(const float* __restrict__ in,
                                unsigned short* __restrict__ out, int n4) {
    int stride = gridDim.x * blockDim.x;
    for (int i = blockIdx.x * blockDim.x + threadIdx.x; i < n4; i += stride) {
        f32x4 v = ((const f32x4*)in)[i];
        uint64_t p = (uint64_t)f2bf(v[0]) | ((uint64_t)f2bf(v[1]) << 16) |
                     ((uint64_t)f2bf(v[2]) << 32) | ((uint64_t)f2bf(v[3]) << 48);
        ((uint64_t*)out)[i] = p;
    }
}

// B [32][N] f32 -> BT [N][32] bf16
__global__ void k_transposeB(const float* __restrict__ in,
                             unsigned short* __restrict__ out, int N) {
    int idx = blockIdx.x * blockDim.x + threadIdx.x;
    if (idx < N * 32) {
        int n = idx >> 5, r = idx & 31;
        out[idx] = f2bf(in[r * N + n]);
    }
}

// ---------------- W_eff prep: dequant + rank-32 LR via one MFMA step ----------------
__global__ __launch_bounds__(256) void k_wprep(
    const unsigned short* __restrict__ BT,   // [Nw][32] bf16
    const unsigned short* __restrict__ Abf,  // [Kw][32] bf16
    const int* __restrict__ q,               // [Nw][Kw] int32
    const float* __restrict__ scale,         // [Nw]
    unsigned short* __restrict__ W,          // [Nw][Kw] bf16 out
    int Nw, int Kw)
{
    __shared__ unsigned short As[128 * 32];
    __shared__ unsigned short Bs[128 * 32];
    const int tid = threadIdx.x, wid = tid >> 6, lane = tid & 63;
    const int wr = wid >> 1, wc = wid & 1;
    const int brow = blockIdx.y * 128;   // n
    const int bcol = blockIdx.x * 128;   // k
    const int srow = wid * 16 + (lane >> 2), scol = (lane & 3) * 8;

    gload16(BT + (size_t)(brow + srow) * 32 + scol,        &As[wid * 512]);
    gload16(BT + (size_t)(brow + 64 + srow) * 32 + scol,   &As[wid * 512 + 2048]);
    gload16(Abf + (size_t)(bcol + srow) * 32 + scol,       &Bs[wid * 512]);
    gload16(Abf + (size_t)(bcol + 64 + srow) * 32 + scol,  &Bs[wid * 512 + 2048]);
    __syncthreads();

    const int fr = lane & 15, kg = (lane >> 4) * 8;
    f32x4 acc[4][4] = {};
    short8 af[4], bfr[4];
#pragma unroll
    for (int i = 0; i < 4; i++)
        af[i] = *(const short8*)&As[(wr * 64 + i * 16 + fr) * 32 + kg];
#pragma unroll
    for (int j = 0; j < 4; j++)
        bfr[j] = *(const short8*)&Bs[(wc * 64 + j * 16 + fr) * 32 + kg];
#pragma unroll
    for (int i = 0; i < 4; i++)
#pragma unroll
        for (int j = 0; j < 4; j++)
            acc[i][j] = __builtin_amdgcn_mfma_f32_16x16x32_bf16(af[i], bfr[j], acc[i][j], 0, 0, 0);

    const int q4 = lane >> 4;
#pragma unroll
    for (int i = 0; i < 4; i++) {
#pragma unroll
        for (int t = 0; t < 4; t++) {
            int n = brow + wr * 64 + i * 16 + q4 * 4 + t;
            float sc = scale[n] * 0.005f;
#pragma unroll
            for (int j = 0; j < 4; j++) {
                int k = bcol + wc * 64 + j * 16 + fr;
                size_t off = (size_t)n * Kw + k;
                float w = ((float)q[off] - 7.5f) * sc + 0.02f * acc[i][j][t];
                W[off] = f2bf(w);
            }
        }
    }
}

// ---------------- main bf16 GEMM: 256x256, BK=64, barrier-free tile body ----------
// C[M][N] = A[M][K] @ B[N][K]^T ; EPI: 0 bf16, 1 h=silu(g)*acc bf16, 2 f32
// 512 threads = 8 waves (2M x 4N); per-wave C 128x64.
// ONE barrier per K-tile. All staging for tile t+1 targets the OTHER buffer
// and is issued right after tile t's boundary -> no LDS region read during
// tile t is written during tile t -> intra-tile barriers unnecessary; the 2
// waves/SIMD free-run and drift, overlapping LDS service with MFMA (m114).
// Boundary (publish, R6-safe): lgkmcnt(0) [own pending ds_reads of the buffer
// about to be overwritten must complete before barrier] + vmcnt(0) [own stage
// loads of buf[t&1], issued ONE TILE ago (~2000cy >> 900cy HBM) => cheap] +
// s_barrier [makes both block-wide].
// Tile body = R5's verified rotation: 8 clusters of 8 MFMA, ds_reads for the
// next cluster issued before each cluster (compiler paces via counted lgkmcnt).
template <int EPI>
__global__ __launch_bounds__(512, 1) void k_gemm256(
    const unsigned short* __restrict__ A,   // [M][K] bf16
    const unsigned short* __restrict__ B,   // [N][K] bf16
    void* __restrict__ C,
    const unsigned short* __restrict__ Gin, // EPI==1: g buffer
    int M, int N, int K)
{
    extern __shared__ unsigned short smem[];   // 65536 elems = 128 KiB
    const int tid = threadIdx.x, wid = tid >> 6, lane = tid & 63;
    const int wr = wid >> 2, wc = wid & 3;

    // T1: bijective XCD swizzle
    const int gx = N >> 8;
    const int nwg = gx * (M >> 8);
    int orig = blockIdx.y * gx + blockIdx.x;
    int q8 = nwg >> 3, r8 = nwg & 7;
    int xcd = orig & 7, lid = orig >> 3;
    int wg = (xcd < r8 ? xcd * (q8 + 1) : r8 * (q8 + 1) + (xcd - r8) * q8) + lid;
    const int bcol = (wg % gx) << 8;
    const int brow = (wg / gx) << 8;

    // staging: quarter c covers rows [c*64 + wid*8, +8); lane l -> row l>>3,
    // LDS slot l&7, pre-swizzled global source slot (l&7)^(l>>3)
    const int rg = lane >> 3;
    const int ss = ((lane & 7) ^ rg) * 8;
    const unsigned short* aS[4];
    const unsigned short* bS[4];
#pragma unroll
    for (int c = 0; c < 4; c++) {
        int row = c * 64 + wid * 8 + rg;
        aS[c] = A + (size_t)(brow + row) * K + ss;
        bS[c] = B + (size_t)(bcol + row) * K + ss;
    }
    const int ldw = wid * 512;   // wave chunk within a 64-row quarter (elems)

    f32x4 acc[8][4] = {};
    short8 afX[4], afY[4], bfX[2], bfY[2];
    const int fr = lane & 15, qk = lane >> 4, f7 = fr & 7;
    const int NT = K >> 6;

    // per-(buffer, kk) read base pointers (literal indices only)
    const unsigned short* aP[2][2];
    const unsigned short* bP[2][2];
#pragma unroll
    for (int b = 0; b < 2; ++b)
#pragma unroll
        for (int kk = 0; kk < 2; ++kk) {
            int swz = (((kk << 2) | qk) ^ f7) << 3;
            aP[b][kk] = smem + b * 32768 + (wr * 64 + fr) * 64 + swz;
            bP[b][kk] = smem + b * 32768 + 16384 + (wc * 32 + fr) * 64 + swz;
        }

#define STG(p, k0, doff) gload16((p) + (k0), smem + (doff) + ldw)
#define STAGE8(BB, k0) { \
    STG(aS[0], k0, (BB)*32768);           STG(aS[1], k0, (BB)*32768 + 4096); \
    STG(aS[2], k0, (BB)*32768 + 8192);    STG(aS[3], k0, (BB)*32768 + 12288); \
    STG(bS[0], k0, (BB)*32768 + 16384);   STG(bS[1], k0, (BB)*32768 + 20480); \
    STG(bS[2], k0, (BB)*32768 + 24576);   STG(bS[3], k0, (BB)*32768 + 28672); }
#define LDA8(dst, P, IH) { _Pragma("unroll") \
    for (int i4 = 0; i4 < 4; ++i4) dst[i4] = *(const short8*)&(P)[(IH)*8192 + i4*1024]; }
#define LDB4(dst, P, JH) { _Pragma("unroll") \
    for (int j2 = 0; j2 < 2; ++j2) dst[j2] = *(const short8*)&(P)[(JH)*8192 + j2*1024]; }
#define MF8(AF, BF, IH, JH) { __builtin_amdgcn_s_setprio(1); \
    _Pragma("unroll") for (int i4 = 0; i4 < 4; ++i4) \
    _Pragma("unroll") for (int j2 = 0; j2 < 2; ++j2) \
        acc[(IH)*4+i4][(JH)*2+j2] = __builtin_amdgcn_mfma_f32_16x16x32_bf16( \
            AF[i4], BF[j2], acc[(IH)*4+i4][(JH)*2+j2], 0, 0, 0); \
    __builtin_amdgcn_s_setprio(0); }

// boundary: publish buf[t&1] (own vmcnt + barrier) and retire this wave's
// ds_reads of the buffer about to be overwritten (own lgkmcnt + barrier).
#define BOUNDARY() { \
    asm volatile("s_waitcnt lgkmcnt(0)" ::: "memory"); \
    asm volatile("s_waitcnt vmcnt(0)" ::: "memory"); \
    __builtin_amdgcn_s_barrier(); }

// One K-tile on buffer BB, barrier-free. DOSTG: stage tile t+1 (k-offset KN)
// into buffer 1-BB, issued after the latency-critical ks0/ks1 reads.
#define TILE(BB, DOSTG, KN) { \
    LDA8(afX, aP[BB][0], 0); LDB4(bfX, bP[BB][0], 0); \
    LDA8(afY, aP[BB][1], 0); LDB4(bfY, bP[BB][1], 0); \
    if (DOSTG) STAGE8(1-(BB), KN); \
    MF8(afX, bfX, 0, 0); \
    LDB4(bfX, bP[BB][0], 1); \
    MF8(afY, bfY, 0, 0); \
    LDB4(bfY, bP[BB][1], 1); \
    MF8(afX, bfX, 0, 1); \
    LDA8(afX, aP[BB][0], 1); \
    MF8(afY, bfY, 0, 1); \
    LDA8(afY, aP[BB][1], 1); \
    MF8(afX, bfX, 1, 1); \
    LDB4(bfX, bP[BB][0], 0); \
    MF8(afY, bfY, 1, 1); \
    LDB4(bfY, bP[BB][1], 0); \
    MF8(afX, bfX, 1, 0); \
    MF8(afY, bfY, 1, 0); }

    // prologue: stage tile0 -> buf0; publish; compute tile0 (stages tile1).
    STAGE8(0, 0);
    asm volatile("s_waitcnt vmcnt(0)" ::: "memory");
    __builtin_amdgcn_s_barrier();
    TILE(0, true, 64);

    int t = 1;
    for (; t + 1 < NT; t += 2) {
        BOUNDARY();
        TILE(1, true, (t + 1) << 6);            // tile t (odd); stage t+1 -> buf0
        BOUNDARY();
        TILE(0, (t + 2) < NT, (t + 2) << 6);    // tile t+1; stage t+2 -> buf1
    }
    BOUNDARY();
    TILE(1, false, 0);                          // final tile (NT even)

#undef TILE
#undef BOUNDARY
#undef MF8
#undef LDB4
#undef LDA8
#undef STAGE8
#undef STG

    // epilogue
    const int q4 = lane >> 4;
#pragma unroll
    for (int i = 0; i < 8; ++i) {
#pragma unroll
        for (int j = 0; j < 4; ++j) {
#pragma unroll
            for (int tt = 0; tt < 4; ++tt) {
                int m = brow + (i >> 2) * 128 + wr * 64 + (i & 3) * 16 + q4 * 4 + tt;
                int n = bcol + (j >> 1) * 128 + wc * 32 + (j & 1) * 16 + fr;
                size_t off = (size_t)m * N + n;
                float v = acc[i][j][tt];
                if (EPI == 0) {
                    ((unsigned short*)C)[off] = f2bf(v);
                } else if (EPI == 1) {
                    float g = bf2f(Gin[off]);
                    float s = g / (1.0f + __expf(-g));   // silu(g)
                    ((unsigned short*)C)[off] = f2bf(s * v);
                } else {
                    ((float*)C)[off] = v;
                }
            }
        }
    }
}

// ---------------- host launch ----------------
extern "C" void kernel_launch(void* const* d_in, const int* in_sizes, int n_in,
                              void* d_out, int out_size, void* d_ws, size_t ws_size,
                              hipStream_t stream) {
    (void)in_sizes; (void)n_in; (void)out_size; (void)ws_size;
    const float* x          = (const float*)d_in[0];
    const int*   gate_q     = (const int*)d_in[1];
    const float* gate_scale = (const float*)d_in[2];
    const float* gate_A     = (const float*)d_in[3];
    const float* gate_B     = (const float*)d_in[4];
    const int*   up_q       = (const int*)d_in[5];
    const float* up_scale   = (const float*)d_in[6];
    const float* up_A       = (const float*)d_in[7];
    const float* up_B       = (const float*)d_in[8];
    const int*   down_q     = (const int*)d_in[9];
    const float* down_scale = (const float*)d_in[10];
    const float* down_A     = (const float*)d_in[11];
    const float* down_B     = (const float*)d_in[12];

    char* ws = (char*)d_ws;
    size_t off = 0;
    auto alloc = [&](size_t bytes) {
        void* p = ws + off; off += (bytes + 255) & ~(size_t)255; return p;
    };
    unsigned short* xbf  = (unsigned short*)alloc((size_t)M_TOK * H_DIM * 2);
    unsigned short* wg   = (unsigned short*)alloc((size_t)I_DIM * H_DIM * 2);
    unsigned short* wu   = (unsigned short*)alloc((size_t)I_DIM * H_DIM * 2);
    unsigned short* wd   = (unsigned short*)alloc((size_t)H_DIM * I_DIM * 2);
    unsigned short* gbuf = (unsigned short*)alloc((size_t)M_TOK * I_DIM * 2);
    unsigned short* AgBf = (unsigned short*)alloc((size_t)H_DIM * 32 * 2);
    unsigned short* AuBf = (unsigned short*)alloc((size_t)H_DIM * 32 * 2);
    unsigned short* AdBf = (unsigned short*)alloc((size_t)I_DIM * 32 * 2);
    unsigned short* BgT  = (unsigned short*)alloc((size_t)I_DIM * 32 * 2);
    unsigned short* BuT  = (unsigned short*)alloc((size_t)I_DIM * 32 * 2);
    unsigned short* BdT  = (unsigned short*)alloc((size_t)H_DIM * 32 * 2);

    (void)hipFuncSetAttribute((const void*)k_gemm256<0>,
        hipFuncAttributeMaxDynamicSharedMemorySize, 131072);
    (void)hipFuncSetAttribute((const void*)k_gemm256<1>,
        hipFuncAttributeMaxDynamicSharedMemorySize, 131072);
    (void)hipFuncSetAttribute((const void*)k_gemm256<2>,
        hipFuncAttributeMaxDynamicSharedMemorySize, 131072);

    // small conversions
    k_conv_f32_bf16<<<128, 256, 0, stream>>>(gate_A, AgBf, (H_DIM * 32) / 4);
    k_conv_f32_bf16<<<128, 256, 0, stream>>>(up_A,   AuBf, (H_DIM * 32) / 4);
    k_conv_f32_bf16<<<344, 256, 0, stream>>>(down_A, AdBf, (I_DIM * 32) / 4);
    k_transposeB<<<(I_DIM * 32 + 255) / 256, 256, 0, stream>>>(gate_B, BgT, I_DIM);
    k_transposeB<<<(I_DIM * 32 + 255) / 256, 256, 0, stream>>>(up_B,   BuT, I_DIM);
    k_transposeB<<<(H_DIM * 32 + 255) / 256, 256, 0, stream>>>(down_B, BdT, H_DIM);
    k_conv_f32_bf16<<<2048, 256, 0, stream>>>(x, xbf, (M_TOK * H_DIM) / 4);

    // W_eff = dequant + 0.02*(A@B)^T   (bf16)
    k_wprep<<<dim3(H_DIM / 128, I_DIM / 128), 256, 0, stream>>>(BgT, AgBf, gate_q, gate_scale, wg, I_DIM, H_DIM);
    k_wprep<<<dim3(H_DIM / 128, I_DIM / 128), 256, 0, stream>>>(BuT, AuBf, up_q,   up_scale,   wu, I_DIM, H_DIM);
    k_wprep<<<dim3(I_DIM / 128, H_DIM / 128), 256, 0, stream>>>(BdT, AdBf, down_q, down_scale, wd, H_DIM, I_DIM);

    // g = x @ Wg^T          (bf16 out)
    k_gemm256<0><<<dim3(I_DIM / 256, M_TOK / 256), 512, 131072, stream>>>(xbf, wg, gbuf, nullptr, M_TOK, I_DIM, H_DIM);
    // h = silu(g) * (x @ Wu^T)   (in-place over g)
    k_gemm256<1><<<dim3(I_DIM / 256, M_TOK / 256), 512, 131072, stream>>>(xbf, wu, gbuf, gbuf, M_TOK, I_DIM, H_DIM);
    // out = h @ Wd^T        (f32)
    k_gemm256<2><<<dim3(H_DIM / 256, M_TOK / 256), 512, 131072, stream>>>(gbuf, wd, d_out, nullptr, M_TOK, H_DIM, I_DIM);
}

// Round 10
// 1171.894 us; speedup vs baseline: 1.1051x; 1.0419x over previous
//
#include <hip/hip_runtime.h>
#include <hip/hip_bf16.h>
#include <stdint.h>

// Problem constants
#define H_DIM 4096
#define I_DIM 11008
#define M_TOK 4096   // B*S = 2*2048

typedef __attribute__((ext_vector_type(8))) short short8;  // 8 bf16 (4 VGPRs)
typedef __attribute__((ext_vector_type(4))) float f32x4;   // 4 fp32

static __device__ __forceinline__ float bf2f(unsigned short u) {
    union { uint32_t i; float f; } v; v.i = ((uint32_t)u) << 16; return v.f;
}
static __device__ __forceinline__ unsigned short f2bf(float f) {
    union { float f; uint32_t i; } v; v.f = f;
    uint32_t r = v.i + 0x7FFF + ((v.i >> 16) & 1);   // RNE
    return (unsigned short)(r >> 16);
}

// async global->LDS, 16B per lane; LDS dest is the wave-uniform base.
static __device__ __forceinline__ void gload16(const void* g, void* l) {
    __builtin_amdgcn_global_load_lds(
        (const __attribute__((address_space(1))) void*)g,
        (__attribute__((address_space(3))) void*)l, 16, 0, 0);
}

// ---------------- small conversion kernels ----------------

__global__ void k_conv_f32_bf16(const float* __restrict__ in,
                                unsigned short* __restrict__ out, int n4) {
    int stride = gridDim.x * blockDim.x;
    for (int i = blockIdx.x * blockDim.x + threadIdx.x; i < n4; i += stride) {
        f32x4 v = ((const f32x4*)in)[i];
        uint64_t p = (uint64_t)f2bf(v[0]) | ((uint64_t)f2bf(v[1]) << 16) |
                     ((uint64_t)f2bf(v[2]) << 32) | ((uint64_t)f2bf(v[3]) << 48);
        ((uint64_t*)out)[i] = p;
    }
}

// B [32][N] f32 -> BT [N][32] bf16
__global__ void k_transposeB(const float* __restrict__ in,
                             unsigned short* __restrict__ out, int N) {
    int idx = blockIdx.x * blockDim.x + threadIdx.x;
    if (idx < N * 32) {
        int n = idx >> 5, r = idx & 31;
        out[idx] = f2bf(in[r * N + n]);
    }
}

// ---------------- W_eff prep: dequant + rank-32 LR via one MFMA step ----------------
__global__ __launch_bounds__(256) void k_wprep(
    const unsigned short* __restrict__ BT,   // [Nw][32] bf16
    const unsigned short* __restrict__ Abf,  // [Kw][32] bf16
    const int* __restrict__ q,               // [Nw][Kw] int32
    const float* __restrict__ scale,         // [Nw]
    unsigned short* __restrict__ W,          // [Nw][Kw] bf16 out
    int Nw, int Kw)
{
    __shared__ unsigned short As[128 * 32];
    __shared__ unsigned short Bs[128 * 32];
    const int tid = threadIdx.x, wid = tid >> 6, lane = tid & 63;
    const int wr = wid >> 1, wc = wid & 1;
    const int brow = blockIdx.y * 128;   // n
    const int bcol = blockIdx.x * 128;   // k
    const int srow = wid * 16 + (lane >> 2), scol = (lane & 3) * 8;

    gload16(BT + (size_t)(brow + srow) * 32 + scol,        &As[wid * 512]);
    gload16(BT + (size_t)(brow + 64 + srow) * 32 + scol,   &As[wid * 512 + 2048]);
    gload16(Abf + (size_t)(bcol + srow) * 32 + scol,       &Bs[wid * 512]);
    gload16(Abf + (size_t)(bcol + 64 + srow) * 32 + scol,  &Bs[wid * 512 + 2048]);
    __syncthreads();

    const int fr = lane & 15, kg = (lane >> 4) * 8;
    f32x4 acc[4][4] = {};
    short8 af[4], bfr[4];
#pragma unroll
    for (int i = 0; i < 4; i++)
        af[i] = *(const short8*)&As[(wr * 64 + i * 16 + fr) * 32 + kg];
#pragma unroll
    for (int j = 0; j < 4; j++)
        bfr[j] = *(const short8*)&Bs[(wc * 64 + j * 16 + fr) * 32 + kg];
#pragma unroll
    for (int i = 0; i < 4; i++)
#pragma unroll
        for (int j = 0; j < 4; j++)
            acc[i][j] = __builtin_amdgcn_mfma_f32_16x16x32_bf16(af[i], bfr[j], acc[i][j], 0, 0, 0);

    const int q4 = lane >> 4;
#pragma unroll
    for (int i = 0; i < 4; i++) {
#pragma unroll
        for (int t = 0; t < 4; t++) {
            int n = brow + wr * 64 + i * 16 + q4 * 4 + t;
            float sc = scale[n] * 0.005f;
#pragma unroll
            for (int j = 0; j < 4; j++) {
                int k = bcol + wc * 64 + j * 16 + fr;
                size_t off = (size_t)n * Kw + k;
                float w = ((float)q[off] - 7.5f) * sc + 0.02f * acc[i][j][t];
                W[off] = f2bf(w);
            }
        }
    }
}

// ---------------- main bf16 GEMM: 256x256, BK=64, role-staggered 8-window tile ----
// C[M][N] = A[M][K] @ B[N][K]^T ; EPI: 0 bf16, 1 h=silu(g)*acc bf16, 2 f32
// 512 threads = 8 waves (2M x 4N); per-wave C 128x64.
// R5 window/stage/cert calendar (verified) + two deltas:
//  (1) B0 re-read eliminated: bf0k0/bf0k1 persist the whole tile (24 reads/tile).
//  (2) WAVE-ROLE STAGGER: role = (wid>>2)&1. Role-E windows: reads-then-MFMA;
//      role-O: MFMA-then-reads. Each SIMD hosts one wave of each role ->
//      LDS pipe and matrix pipe are both fed from window start instead of
//      alternating (phase-lock serialization was ~sum of the two pipe times).
//      Order is enforced by program order + setprio + sched_group_barrier.
// Window w consumes reads issued in window w-1 (register rotation afK0/afK1;
// bf0/bf1 persistent). MFMA map: w0 (0,0)k0; w1 (0,0)k1; w2 (0,1)k0; w3 (0,1)k1;
// w4 (1,1)k0; w5 (1,1)k1; w6 (1,0)k0; w7 (1,0)k1.
// Reads: w0 {A0k1,B0k1}; w1 {B1k0}; w2 {B1k1}; w3 {A1k0}; w4 {A1k1}; w7 {A0k0',B0k0'}.
// Stage calendar (per tile t, buf BB): w0 B0(t+1)->1-BB; w2 A0(t+2)->BB;
// w4 B1(t+2)->BB; w6 A1(t+2)->BB. Cert: end-w3 vmcnt(2) pre-BAR_4 => tile t+1
// fully published block-wide at BAR_4 (first read of it: w7). Every stage
// overwrites a region whose last LDS read completed >=1 barrier earlier.
template <int EPI>
__global__ __launch_bounds__(512, 1) void k_gemm256(
    const unsigned short* __restrict__ A,   // [M][K] bf16
    const unsigned short* __restrict__ B,   // [N][K] bf16
    void* __restrict__ C,
    const unsigned short* __restrict__ Gin, // EPI==1: g buffer
    int M, int N, int K)
{
    extern __shared__ unsigned short smem[];   // 65536 elems = 128 KiB
    const int tid = threadIdx.x, wid = tid >> 6, lane = tid & 63;
    const int wr = wid >> 2, wc = wid & 3;

    // T1: bijective XCD swizzle
    const int gx = N >> 8;
    const int nwg = gx * (M >> 8);
    int orig = blockIdx.y * gx + blockIdx.x;
    int q8 = nwg >> 3, r8 = nwg & 7;
    int xcd = orig & 7, lid = orig >> 3;
    int wg = (xcd < r8 ? xcd * (q8 + 1) : r8 * (q8 + 1) + (xcd - r8) * q8) + lid;
    const int bcol = (wg % gx) << 8;
    const int brow = (wg / gx) << 8;

    // staging: quarter c covers rows [c*64 + wid*8, +8); lane l -> row l>>3,
    // LDS slot l&7, pre-swizzled global source slot (l&7)^(l>>3)
    const int rg = lane >> 3;
    const int ss = ((lane & 7) ^ rg) * 8;
    const unsigned short* aS[4];
    const unsigned short* bS[4];
#pragma unroll
    for (int c = 0; c < 4; c++) {
        int row = c * 64 + wid * 8 + rg;
        aS[c] = A + (size_t)(brow + row) * K + ss;
        bS[c] = B + (size_t)(bcol + row) * K + ss;
    }
    const int ldw = wid * 512;   // wave chunk within a 64-row quarter (elems)

    f32x4 acc[8][4] = {};
    short8 afK0[4], afK1[4];          // A frags, kk=0 / kk=1 (rotate per half)
    short8 bf0k0[2], bf0k1[2];        // B-half0, persistent whole tile
    short8 bf1k0[2], bf1k1[2];        // B-half1
    const int fr = lane & 15, qk = lane >> 4, f7 = fr & 7;
    const int NT = K >> 6;

    // per-(buffer, kk) read base pointers (literal indices only)
    const unsigned short* aP[2][2];
    const unsigned short* bP[2][2];
#pragma unroll
    for (int b = 0; b < 2; ++b)
#pragma unroll
        for (int kk = 0; kk < 2; ++kk) {
            int swz = (((kk << 2) | qk) ^ f7) << 3;
            aP[b][kk] = smem + b * 32768 + (wr * 64 + fr) * 64 + swz;
            bP[b][kk] = smem + b * 32768 + 16384 + (wc * 32 + fr) * 64 + swz;
        }

#define STG(p, k0, doff) gload16((p) + (k0), smem + (doff) + ldw)
#define SB0STG(BB, kN) { STG(bS[0], kN, (1-(BB))*32768 + 16384); \
                         STG(bS[1], kN, (1-(BB))*32768 + 20480); }
#define SA0STG(BB, k2) { STG(aS[0], k2, (BB)*32768); \
                         STG(aS[1], k2, (BB)*32768 + 4096); }
#define SB1STG(BB, k2) { STG(bS[2], k2, (BB)*32768 + 24576); \
                         STG(bS[3], k2, (BB)*32768 + 28672); }
#define SA1STG(BB, k2) { STG(aS[2], k2, (BB)*32768 + 8192); \
                         STG(aS[3], k2, (BB)*32768 + 12288); }
#define LDA8(dst, P, IH) { _Pragma("unroll") \
    for (int i4 = 0; i4 < 4; ++i4) dst[i4] = *(const short8*)&(P)[(IH)*8192 + i4*1024]; }
#define LDB4(dst, P, JH) { _Pragma("unroll") \
    for (int j2 = 0; j2 < 2; ++j2) dst[j2] = *(const short8*)&(P)[(JH)*8192 + j2*1024]; }
#define MFQ(AF, BF, IH, JH) { __builtin_amdgcn_s_setprio(1); \
    _Pragma("unroll") for (int i4 = 0; i4 < 4; ++i4) \
    _Pragma("unroll") for (int j2 = 0; j2 < 2; ++j2) \
        acc[(IH)*4+i4][(JH)*2+j2] = __builtin_amdgcn_mfma_f32_16x16x32_bf16( \
            AF[i4], BF[j2], acc[(IH)*4+i4][(JH)*2+j2], 0, 0, 0); \
    __builtin_amdgcn_s_setprio(0); }
#define BAR() __builtin_amdgcn_s_barrier()
#define SGB(m, n) __builtin_amdgcn_sched_group_barrier(m, n, 0)

// window bodies: role-E = reads first; role-O = MFMA first.
#define WRE(RD, NRD, MF) { RD MF SGB(0x100, NRD); SGB(0x8, 8); }
#define WRO(RD, NRD, MF) { MF RD SGB(0x8, 8); SGB(0x100, NRD); }

#define CERT2 asm volatile("s_waitcnt vmcnt(2)" ::: "memory")
#define CERT0 asm volatile("s_waitcnt vmcnt(0)" ::: "memory")
#define CERTN ((void)0)

// full tile: stages + cert + next-tile w7 reads.
#define TILE(W, BB, kN, k2, SB0, S2, CRT) { \
    BAR(); if (SB0) { SB0STG(BB, kN); } \
    W({ LDA8(afK1, aP[BB][1], 0); LDB4(bf0k1, bP[BB][1], 0); }, 6, \
      MFQ(afK0, bf0k0, 0, 0)); \
    BAR(); \
    W({ LDB4(bf1k0, bP[BB][0], 1); }, 2, MFQ(afK1, bf0k1, 0, 0)); \
    BAR(); if (S2) { SA0STG(BB, k2); } \
    W({ LDB4(bf1k1, bP[BB][1], 1); }, 2, MFQ(afK0, bf1k0, 0, 1)); \
    BAR(); \
    W({ LDA8(afK0, aP[BB][0], 1); }, 4, MFQ(afK1, bf1k1, 0, 1)); \
    CRT; \
    BAR(); if (S2) { SB1STG(BB, k2); } \
    W({ LDA8(afK1, aP[BB][1], 1); }, 4, MFQ(afK0, bf1k0, 1, 1)); \
    BAR(); \
    MFQ(afK1, bf1k1, 1, 1); \
    BAR(); if (S2) { SA1STG(BB, k2); } \
    MFQ(afK0, bf0k0, 1, 0); \
    BAR(); \
    W({ LDA8(afK0, aP[1-(BB)][0], 0); LDB4(bf0k0, bP[1-(BB)][0], 0); }, 6, \
      MFQ(afK1, bf0k1, 1, 0)); \
}

// final tile: no stages, no cert, no next-tile reads.
#define TILE_END(W, BB) { \
    BAR(); \
    W({ LDA8(afK1, aP[BB][1], 0); LDB4(bf0k1, bP[BB][1], 0); }, 6, \
      MFQ(afK0, bf0k0, 0, 0)); \
    BAR(); \
    W({ LDB4(bf1k0, bP[BB][0], 1); }, 2, MFQ(afK1, bf0k1, 0, 0)); \
    BAR(); \
    W({ LDB4(bf1k1, bP[BB][1], 1); }, 2, MFQ(afK0, bf1k0, 0, 1)); \
    BAR(); \
    W({ LDA8(afK0, aP[BB][0], 1); }, 4, MFQ(afK1, bf1k1, 0, 1)); \
    BAR(); \
    W({ LDA8(afK1, aP[BB][1], 1); }, 4, MFQ(afK0, bf1k0, 1, 1)); \
    BAR(); \
    MFQ(afK1, bf1k1, 1, 1); \
    BAR(); \
    MFQ(afK0, bf0k0, 1, 0); \
    BAR(); \
    MFQ(afK1, bf0k1, 1, 0); \
}

#define KLOOP(W) { \
    int t = 0; \
    for (; t < NT - 2; t += 2) { \
        TILE(W, 0, (t + 1) << 6, (t + 2) << 6, 1, 1, CERT2); \
        TILE(W, 1, (t + 2) << 6, (t + 3) << 6, 1, 1, CERT2); \
    } \
    TILE(W, 0, (t + 1) << 6, 0, 1, 0, CERT0); \
    TILE_END(W, 1); \
}

    // prologue: tile0 full (A0,B0,B1,A1) then tile1 {A0,B1,A1}; B0(1) at w0.
    SA0STG(0, 0); SB0STG(1, 0); SB1STG(0, 0); SA1STG(0, 0);
    SA0STG(1, 64); SB1STG(1, 64); SA1STG(1, 64);
    asm volatile("s_waitcnt vmcnt(6)" ::: "memory");   // tile 0 landed
    BAR();
    LDA8(afK0, aP[0][0], 0); LDB4(bf0k0, bP[0][0], 0); // reads for w0(tile0)

    if (((wid >> 2) & 1) == 0) {
        KLOOP(WRE);
    } else {
        KLOOP(WRO);
    }

#undef KLOOP
#undef TILE_END
#undef TILE
#undef CERTN
#undef CERT0
#undef CERT2
#undef WRO
#undef WRE
#undef SGB
#undef BAR
#undef MFQ
#undef LDB4
#undef LDA8
#undef SA1STG
#undef SB1STG
#undef SA0STG
#undef SB0STG
#undef STG

    // epilogue
    const int q4 = lane >> 4;
#pragma unroll
    for (int i = 0; i < 8; ++i) {
#pragma unroll
        for (int j = 0; j < 4; ++j) {
#pragma unroll
            for (int tt = 0; tt < 4; ++tt) {
                int m = brow + (i >> 2) * 128 + wr * 64 + (i & 3) * 16 + q4 * 4 + tt;
                int n = bcol + (j >> 1) * 128 + wc * 32 + (j & 1) * 16 + fr;
                size_t off = (size_t)m * N + n;
                float v = acc[i][j][tt];
                if (EPI == 0) {
                    ((unsigned short*)C)[off] = f2bf(v);
                } else if (EPI == 1) {
                    float g = bf2f(Gin[off]);
                    float s = g / (1.0f + __expf(-g));   // silu(g)
                    ((unsigned short*)C)[off] = f2bf(s * v);
                } else {
                    ((float*)C)[off] = v;
                }
            }
        }
    }
}

// ---------------- host launch ----------------
extern "C" void kernel_launch(void* const* d_in, const int* in_sizes, int n_in,
                              void* d_out, int out_size, void* d_ws, size_t ws_size,
                              hipStream_t stream) {
    (void)in_sizes; (void)n_in; (void)out_size; (void)ws_size;
    const float* x          = (const float*)d_in[0];
    const int*   gate_q     = (const int*)d_in[1];
    const float* gate_scale = (const float*)d_in[2];
    const float* gate_A     = (const float*)d_in[3];
    const float* gate_B     = (const float*)d_in[4];
    const int*   up_q       = (const int*)d_in[5];
    const float* up_scale   = (const float*)d_in[6];
    const float* up_A       = (const float*)d_in[7];
    const float* up_B       = (const float*)d_in[8];
    const int*   down_q     = (const int*)d_in[9];
    const float* down_scale = (const float*)d_in[10];
    const float* down_A     = (const float*)d_in[11];
    const float* down_B     = (const float*)d_in[12];

    char* ws = (char*)d_ws;
    size_t off = 0;
    auto alloc = [&](size_t bytes) {
        void* p = ws + off; off += (bytes + 255) & ~(size_t)255; return p;
    };
    unsigned short* xbf  = (unsigned short*)alloc((size_t)M_TOK * H_DIM * 2);
    unsigned short* wg   = (unsigned short*)alloc((size_t)I_DIM * H_DIM * 2);
    unsigned short* wu   = (unsigned short*)alloc((size_t)I_DIM * H_DIM * 2);
    unsigned short* wd   = (unsigned short*)alloc((size_t)H_DIM * I_DIM * 2);
    unsigned short* gbuf = (unsigned short*)alloc((size_t)M_TOK * I_DIM * 2);
    unsigned short* AgBf = (unsigned short*)alloc((size_t)H_DIM * 32 * 2);
    unsigned short* AuBf = (unsigned short*)alloc((size_t)H_DIM * 32 * 2);
    unsigned short* AdBf = (unsigned short*)alloc((size_t)I_DIM * 32 * 2);
    unsigned short* BgT  = (unsigned short*)alloc((size_t)I_DIM * 32 * 2);
    unsigned short* BuT  = (unsigned short*)alloc((size_t)I_DIM * 32 * 2);
    unsigned short* BdT  = (unsigned short*)alloc((size_t)H_DIM * 32 * 2);

    (void)hipFuncSetAttribute((const void*)k_gemm256<0>,
        hipFuncAttributeMaxDynamicSharedMemorySize, 131072);
    (void)hipFuncSetAttribute((const void*)k_gemm256<1>,
        hipFuncAttributeMaxDynamicSharedMemorySize, 131072);
    (void)hipFuncSetAttribute((const void*)k_gemm256<2>,
        hipFuncAttributeMaxDynamicSharedMemorySize, 131072);

    // small conversions
    k_conv_f32_bf16<<<128, 256, 0, stream>>>(gate_A, AgBf, (H_DIM * 32) / 4);
    k_conv_f32_bf16<<<128, 256, 0, stream>>>(up_A,   AuBf, (H_DIM * 32) / 4);
    k_conv_f32_bf16<<<344, 256, 0, stream>>>(down_A, AdBf, (I_DIM * 32) / 4);
    k_transposeB<<<(I_DIM * 32 + 255) / 256, 256, 0, stream>>>(gate_B, BgT, I_DIM);
    k_transposeB<<<(I_DIM * 32 + 255) / 256, 256, 0, stream>>>(up_B,   BuT, I_DIM);
    k_transposeB<<<(H_DIM * 32 + 255) / 256, 256, 0, stream>>>(down_B, BdT, H_DIM);
    k_conv_f32_bf16<<<2048, 256, 0, stream>>>(x, xbf, (M_TOK * H_DIM) / 4);

    // W_eff = dequant + 0.02*(A@B)^T   (bf16)
    k_wprep<<<dim3(H_DIM / 128, I_DIM / 128), 256, 0, stream>>>(BgT, AgBf, gate_q, gate_scale, wg, I_DIM, H_DIM);
    k_wprep<<<dim3(H_DIM / 128, I_DIM / 128), 256, 0, stream>>>(BuT, AuBf, up_q,   up_scale,   wu, I_DIM, H_DIM);
    k_wprep<<<dim3(I_DIM / 128, H_DIM / 128), 256, 0, stream>>>(BdT, AdBf, down_q, down_scale, wd, H_DIM, I_DIM);

    // g = x @ Wg^T          (bf16 out)
    k_gemm256<0><<<dim3(I_DIM / 256, M_TOK / 256), 512, 131072, stream>>>(xbf, wg, gbuf, nullptr, M_TOK, I_DIM, H_DIM);
    // h = silu(g) * (x @ Wu^T)   (in-place over g)
    k_gemm256<1><<<dim3(I_DIM / 256, M_TOK / 256), 512, 131072, stream>>>(xbf, wu, gbuf, gbuf, M_TOK, I_DIM, H_DIM);
    // out = h @ Wd^T        (f32)
    k_gemm256<2><<<dim3(H_DIM / 256, M_TOK / 256), 512, 131072, stream>>>(gbuf, wd, d_out, nullptr, M_TOK, H_DIM, I_DIM);
}